// Round 2
// baseline (162.721 us; speedup 1.0000x reference)
//
#include <hip/hip_runtime.h>
#include <hip/hip_bf16.h>

#define B_ 2
#define T_ 2048
#define D_ 1024
#define H_ 16
#define DH_ 64

typedef __attribute__((ext_vector_type(8))) short bf16x8;
typedef __attribute__((ext_vector_type(4))) short bf16x4;
typedef __attribute__((ext_vector_type(4))) float f32x4;
typedef __attribute__((ext_vector_type(8))) unsigned short u16x8;

__device__ __forceinline__ unsigned short f2bf(float f) {   // RNE fp32->bf16
    unsigned int u = __float_as_uint(f);
    return (unsigned short)((u + 0x7FFFu + ((u >> 16) & 1u)) >> 16);
}

// K=16 bf16 MFMA; guard so the host pass never touches the builtin.
__device__ __forceinline__ f32x4 mfma16(bf16x4 a, bf16x4 b, f32x4 c) {
#if defined(__HIP_DEVICE_COMPILE__)
    return __builtin_amdgcn_mfma_f32_16x16x16bf16_1k(a, b, c, 0, 0, 0);
#else
    return c;
#endif
}

// ---------------------------------------------------------------------------
// Launch 1: pure streaming conversions (independent blocks).
//   [0,512)    : k  fp32 -> kb  bf16   (interleaved, coalesced per instr)
//   [512,1024) : x  fp32 -> xb  bf16
//   [1024,1152): Wq fp32 -> wqb bf16
//   [1152,2176): v[b,h,t,dh] -> vt[b,h,dh,t] bf16 (64x64 LDS transpose)
// R1 post-mortem: this kernel is ~15 us either way; not the lever.
// ---------------------------------------------------------------------------
__global__ __launch_bounds__(256) void conv_kernel(
    const float* __restrict__ k, const float* __restrict__ v,
    const float* __restrict__ x, const float* __restrict__ Wq,
    unsigned short* __restrict__ kb, unsigned short* __restrict__ vt,
    unsigned short* __restrict__ xb, unsigned short* __restrict__ wqb)
{
    __shared__ float Ts[64][65];
    const int tid = threadIdx.x;
    const int bi = blockIdx.x;

    if (bi < 1152) {                      // ---- flat conversions ----
        const float* src;
        unsigned short* dst;
        if (bi < 512)       { src = k  + (size_t)bi * 8192;
                              dst = kb  + (size_t)bi * 8192; }
        else if (bi < 1024) { src = x  + (size_t)(bi - 512) * 8192;
                              dst = xb  + (size_t)(bi - 512) * 8192; }
        else                { src = Wq + (size_t)(bi - 1024) * 8192;
                              dst = wqb + (size_t)(bi - 1024) * 8192; }
        #pragma unroll
        for (int u = 0; u < 8; ++u) {
            const int o = u * 1024 + tid * 4;
            const float4 a = *(const float4*)(src + o);
            ushort4 s;
            s.x = f2bf(a.x); s.y = f2bf(a.y);
            s.z = f2bf(a.z); s.w = f2bf(a.w);
            *(ushort4*)(dst + o) = s;
        }
        return;
    }

    // ---- v transpose+convert ----
    const int idx = bi - 1152;
    const int t0 = (idx & 31) * 64;
    const int hb = idx >> 5;
    const size_t bh = (size_t)(hb >> 4) * H_ + (hb & 15);
    #pragma unroll
    for (int u = 0; u < 4; ++u) {
        const int tr = u * 16 + (tid >> 4);
        const int dc = (tid & 15) * 4;
        const float4 r = *(const float4*)(v + (bh * T_ + t0 + tr) * DH_ + dc);
        Ts[tr][dc + 0] = r.x; Ts[tr][dc + 1] = r.y;
        Ts[tr][dc + 2] = r.z; Ts[tr][dc + 3] = r.w;
    }
    __syncthreads();
    #pragma unroll
    for (int u = 0; u < 4; ++u) {
        const int dh = u * 16 + (tid >> 4);
        const int tc = (tid & 15) * 4;
        ushort4 o;
        o.x = f2bf(Ts[tc + 0][dh]); o.y = f2bf(Ts[tc + 1][dh]);
        o.z = f2bf(Ts[tc + 2][dh]); o.w = f2bf(Ts[tc + 3][dh]);
        *(ushort4*)(vt + (bh * DH_ + dh) * T_ + t0 + tc) = o;
    }
}

// ---------------------------------------------------------------------------
// Launch 2: mega-attention (qproj fused). 1024 blocks, 64 q-rows each,
// 4 waves x 16 rows, 4 blocks/CU resident (16 waves/CU).
//
// R2: BALANCED STATIC MAP. All 1024 blocks are co-resident (4/CU); CU(bi)
// is a function of (bi mod 256) (XCD = bi%8 striping), so CU c receives
// q-tile groups {g, g+8, g+16, g+24}, g=(bi mod 256)>>5. Map group G->qt
// via the constant-sum partition {g, 15-g, 16+g, 31-g} (sum 62 for every
// g), so every CU gets identical causal work. (R1's 512-block pairing
// balanced work but halved occupancy -> 74 us; R0's 31-G map left CUs at
// 80 vs 66 avg units -> makespan +21%.)
//
// Phase 1: Q^T = Wq_h * x^T, bf16 staged, double-buffered, 1 barrier/iter.
//   acc C-layout = Q^T [dh = w*16+l4*4+r][qrow = nt*16+l15]; bounced
//   through Qs (overlaid on dead Xs1) -> B-operand Q fragments.
//   Q is scaled by (1/sqrt(D))*log2(e) so softmax runs in exp2 domain
//   (saves one v_mul per exp on the serial softmax chain).
// Phase 2: transposed-S flash loop, double-buffered K/V, stride 72,
//   1 barrier/iter, P^T in registers, O^T = V^T * P^T, fused residual.
//
// LDS regions (36864 B): phase1 Ws0=0, Xs0=9216, Ws1=18432, Xs1=27648;
// Qs=27648; phase2 Ks0=0, Ks1=9216, Vs0=18432, Vs1=27648. All reuses are
// barrier-separated.
// ---------------------------------------------------------------------------
__global__ __launch_bounds__(256, 4) void mega_attn(
    const unsigned short* __restrict__ xb,   // [B,T,D]   bf16
    const unsigned short* __restrict__ wqb,  // [D,D]     bf16
    const unsigned short* __restrict__ kb,   // [B,H,T,DH] bf16
    const unsigned short* __restrict__ vt,   // [B,H,DH,T] bf16
    const float* __restrict__ xg,            // [B,T,D] fp32 (residual)
    float* __restrict__ out)                 // [B,T,D] fp32
{
    __shared__ __align__(16) char lds_raw[36864];
    unsigned short (*Ws0)[72] = (unsigned short(*)[72])(lds_raw);
    unsigned short (*Xs0)[72] = (unsigned short(*)[72])(lds_raw + 9216);
    unsigned short (*Ws1)[72] = (unsigned short(*)[72])(lds_raw + 18432);
    unsigned short (*Xs1)[72] = (unsigned short(*)[72])(lds_raw + 27648);
    unsigned short (*Qs)[72]  = (unsigned short(*)[72])(lds_raw + 27648);
    unsigned short (*Ks0)[72] = (unsigned short(*)[72])(lds_raw);
    unsigned short (*Ks1)[72] = (unsigned short(*)[72])(lds_raw + 9216);
    unsigned short (*Vs0)[72] = (unsigned short(*)[72])(lds_raw + 18432);
    unsigned short (*Vs1)[72] = (unsigned short(*)[72])(lds_raw + 27648);

    const int tid = threadIdx.x;
    const int lane = tid & 63;
    const int w = tid >> 6;
    const int l15 = lane & 15, l4 = lane >> 4;
    const int bi = blockIdx.x;

    // balanced qt map: G in quarter q, offset r -> {r, 15-r, 16+r, 31-r}
    const int G = bi >> 5;
    const int r_ = G & 7, q_ = G >> 3;
    const int qt = (q_ == 0) ? r_ : (q_ == 1) ? 15 - r_
                 : (q_ == 2) ? 16 + r_ : 31 - r_;

    const int hb = bi & 31;
    const int h = hb & 15, b = hb >> 4;
    const int q0 = qt * 64;
    const size_t bh = (size_t)b * H_ + h;

    const int srow = tid >> 2;               // staging row 0..63
    const int scol = (tid & 3) * 16;         // staging col (shorts)

    // ---- Phase 1: Q^T tile build (bf16 staged, dbuf, 1 barrier/iter) ----
    f32x4 acc[4] = {};
    {
        const unsigned short* xg0 = xb  + ((size_t)b * T_ + q0 + srow) * D_ + scol;
        const unsigned short* wg0 = wqb + (size_t)(h * 64 + srow) * D_ + scol;

        // stage iter 0 into buffer 0
        uint4 xr0 = *(const uint4*)(xg0);
        uint4 xr1 = *(const uint4*)(xg0 + 8);
        uint4 wr0 = *(const uint4*)(wg0);
        uint4 wr1 = *(const uint4*)(wg0 + 8);
        *(uint4*)&Xs0[srow][scol] = xr0;
        *(uint4*)&Xs0[srow][scol + 8] = xr1;
        *(uint4*)&Ws0[srow][scol] = wr0;
        *(uint4*)&Ws0[srow][scol + 8] = wr1;
        __syncthreads();

        int p = 0;
        for (int it = 0; it < 16; ++it) {
            if (it < 15) {
                const int kk = (it + 1) * 64;
                xr0 = *(const uint4*)(xg0 + kk);
                xr1 = *(const uint4*)(xg0 + kk + 8);
                wr0 = *(const uint4*)(wg0 + kk);
                wr1 = *(const uint4*)(wg0 + kk + 8);
            }
            unsigned short (*Wp)[72] = p ? Ws1 : Ws0;
            unsigned short (*Xp)[72] = p ? Xs1 : Xs0;
            #pragma unroll
            for (int kc = 0; kc < 2; ++kc) {
                const bf16x8 wf = *(const bf16x8*)&Wp[w * 16 + l15][kc * 32 + l4 * 8];
                #pragma unroll
                for (int nt = 0; nt < 4; ++nt) {
                    const bf16x8 xf = *(const bf16x8*)&Xp[nt * 16 + l15][kc * 32 + l4 * 8];
                    acc[nt] = __builtin_amdgcn_mfma_f32_16x16x32_bf16(wf, xf, acc[nt], 0, 0, 0);
                }
            }
            if (it < 15) {
                unsigned short (*Wn)[72] = p ? Ws0 : Ws1;
                unsigned short (*Xn)[72] = p ? Xs0 : Xs1;
                *(uint4*)&Xn[srow][scol] = xr0;
                *(uint4*)&Xn[srow][scol + 8] = xr1;
                *(uint4*)&Wn[srow][scol] = wr0;
                *(uint4*)&Wn[srow][scol + 8] = wr1;
                __syncthreads();
                p ^= 1;
            }
        }
    }
    __syncthreads();   // final phase-1 buffer (Ws1/Xs1) fully consumed

    // Qs write: acc[nt][r] = Q^T[dh = w*16+l4*4+r][qrow = nt*16+l15]
    // scale folds in log2(e): softmax computed as 2^(s' - m') with
    // s' = s*log2e — weights identical to exp-domain softmax.
    {
        const float qscale = (1.0f / 32.0f) * 1.4426950408889634f;
        #pragma unroll
        for (int nt = 0; nt < 4; ++nt) {
            ushort4 o;
            o.x = f2bf(acc[nt][0] * qscale); o.y = f2bf(acc[nt][1] * qscale);
            o.z = f2bf(acc[nt][2] * qscale); o.w = f2bf(acc[nt][3] * qscale);
            *(ushort4*)&Qs[nt * 16 + l15][w * 16 + l4 * 4] = o;
        }
    }
    __syncthreads();   // all Qs writes visible (cross-wave)

    // Q B-fragments: lane l15 = qrow (w*16+l15), k = dh
    bf16x8 qf[2];
    #pragma unroll
    for (int kc = 0; kc < 2; ++kc)
        qf[kc] = *(const bf16x8*)&Qs[w * 16 + l15][kc * 32 + l4 * 8];

    f32x4 o_acc[4] = {};                     // O^T: dh = mt*16+l4*4+r, qrow = l15
    float m_i = -INFINITY, l_i = 0.0f;

    // stage tile j0=0 into buffer 0 (Ks0/Vs0 don't overlap Qs)
    {
        const unsigned short* gk = kb + (bh * T_ + srow) * DH_ + scol;
        *(uint4*)&Ks0[srow][scol] = *(const uint4*)gk;
        *(uint4*)&Ks0[srow][scol + 8] = *(const uint4*)(gk + 8);
        const unsigned short* gv = vt + (bh * DH_ + srow) * T_ + scol;
        *(uint4*)&Vs0[srow][scol] = *(const uint4*)gv;
        *(uint4*)&Vs0[srow][scol + 8] = *(const uint4*)(gv + 8);
    }
    __syncthreads();   // also orders qf reads before any later Vs1 write

    int p = 0;
    for (int j0 = 0; j0 <= q0; j0 += 64) {
        unsigned short (*Ksp)[72] = p ? Ks1 : Ks0;
        unsigned short (*Vsp)[72] = p ? Vs1 : Vs0;
        unsigned short (*Ksn)[72] = p ? Ks0 : Ks1;
        unsigned short (*Vsn)[72] = p ? Vs0 : Vs1;

        // prefetch next tile into registers (valid-but-discarded addr on last)
        const int jn = (j0 + 64 <= q0) ? j0 + 64 : 0;
        uint4 kr0, kr1, vr0, vr1;
        {
            const unsigned short* gk = kb + (bh * T_ + jn + srow) * DH_ + scol;
            kr0 = *(const uint4*)gk;
            kr1 = *(const uint4*)(gk + 8);
            const unsigned short* gv = vt + (bh * DH_ + srow) * T_ + jn + scol;
            vr0 = *(const uint4*)gv;
            vr1 = *(const uint4*)(gv + 8);
        }

        // S^T = K * Q^T : st[nt] keys nt*16 + l4*4+r, qrow = w*16+l15
        f32x4 st[4] = {};
        #pragma unroll
        for (int kc = 0; kc < 2; ++kc) {
            #pragma unroll
            for (int nt = 0; nt < 4; ++nt) {
                const bf16x8 kf = *(const bf16x8*)&Ksp[nt * 16 + l15][kc * 32 + l4 * 8];
                st[nt] = __builtin_amdgcn_mfma_f32_16x16x32_bf16(kf, qf[kc], st[nt], 0, 0, 0);
            }
        }

        // causal mask (diagonal tile only)
        if (j0 == q0) {
            const int thr = w * 16 + l15 - l4 * 4;   // mask if nt*16+r > thr
            #pragma unroll
            for (int nt = 0; nt < 4; ++nt)
                #pragma unroll
                for (int r = 0; r < 4; ++r)
                    if (nt * 16 + r > thr) st[nt][r] = -INFINITY;
        }

        // online softmax (exp2 domain): 16 in-lane values + 2-shfl butterfly
        float rm = -INFINITY;
        #pragma unroll
        for (int nt = 0; nt < 4; ++nt)
            #pragma unroll
            for (int r = 0; r < 4; ++r) rm = fmaxf(rm, st[nt][r]);
        rm = fmaxf(rm, __shfl_xor(rm, 16));
        rm = fmaxf(rm, __shfl_xor(rm, 32));
        const float mn = fmaxf(m_i, rm);
        const float alpha = exp2f(m_i - mn);
        float rs = 0.0f;
        #pragma unroll
        for (int nt = 0; nt < 4; ++nt)
            #pragma unroll
            for (int r = 0; r < 4; ++r) {
                const float pv = exp2f(st[nt][r] - mn);
                st[nt][r] = pv;
                rs += pv;
            }
        rs += __shfl_xor(rs, 16);
        rs += __shfl_xor(rs, 32);
        l_i = l_i * alpha + rs;
        m_i = mn;
        #pragma unroll
        for (int mt = 0; mt < 4; ++mt)
            #pragma unroll
            for (int r = 0; r < 4; ++r) o_acc[mt][r] *= alpha;

        // pack P^T into K=16 B-frags (v_perm truncation, 2 vals/op)
        bf16x4 pf[4];
        #pragma unroll
        for (int nt = 0; nt < 4; ++nt) {
            union { unsigned int u[2]; bf16x4 s; } cv;
            cv.u[0] = __builtin_amdgcn_perm(__float_as_uint(st[nt][1]),
                                            __float_as_uint(st[nt][0]), 0x07060302u);
            cv.u[1] = __builtin_amdgcn_perm(__float_as_uint(st[nt][3]),
                                            __float_as_uint(st[nt][2]), 0x07060302u);
            pf[nt] = cv.s;
        }

        // O^T += V^T * P^T  (A = V^T from LDS, B = P^T in registers)
        #pragma unroll
        for (int c = 0; c < 4; ++c) {
            #pragma unroll
            for (int mt = 0; mt < 4; ++mt) {
                const bf16x4 vf = *(const bf16x4*)&Vsp[mt * 16 + l15][c * 16 + l4 * 4];
                o_acc[mt] = mfma16(vf, pf[c], o_acc[mt]);
            }
        }

        // write prefetched tile to the other buffer, single barrier
        *(uint4*)&Ksn[srow][scol] = kr0;
        *(uint4*)&Ksn[srow][scol + 8] = kr1;
        *(uint4*)&Vsn[srow][scol] = vr0;
        *(uint4*)&Vsn[srow][scol + 8] = vr1;
        __syncthreads();
        p ^= 1;
    }

    // epilogue: out = x + O^T / l   (dh = mt*16 + l4*4+r, qrow = l15)
    const float inv = 1.0f / l_i;
    const int qrow = q0 + w * 16 + l15;
    #pragma unroll
    for (int mt = 0; mt < 4; ++mt) {
        #pragma unroll
        for (int r = 0; r < 4; ++r) {
            const int d = h * DH_ + mt * 16 + l4 * 4 + r;
            const size_t off = ((size_t)b * T_ + qrow) * D_ + d;
            out[off] = xg[off] + o_acc[mt][r] * inv;
        }
    }
}

extern "C" void kernel_launch(void* const* d_in, const int* in_sizes, int n_in,
                              void* d_out, int out_size, void* d_ws, size_t ws_size,
                              hipStream_t stream) {
    const float* x  = (const float*)d_in[0];
    const float* k  = (const float*)d_in[1];
    const float* v  = (const float*)d_in[2];
    const float* Wq = (const float*)d_in[3];
    float* out = (float*)d_out;

    const size_t NE = (size_t)B_ * H_ * T_ * DH_;   // 4M elements
    unsigned short* kb  = (unsigned short*)d_ws;    // 8 MB
    unsigned short* vt  = kb + NE;                  // 8 MB
    unsigned short* xb  = vt + NE;                  // 8 MB
    unsigned short* wqb = xb + NE;                  // 2 MB

    conv_kernel<<<2176, 256, 0, stream>>>(k, v, x, Wq, kb, vt, xb, wqb);
    mega_attn<<<1024, 256, 0, stream>>>(xb, wqb, kb, vt, x, out);
}

// Round 3
// 160.749 us; speedup vs baseline: 1.0123x; 1.0123x over previous
//
#include <hip/hip_runtime.h>
#include <hip/hip_bf16.h>

#define B_ 2
#define T_ 2048
#define D_ 1024
#define H_ 16
#define DH_ 64

typedef __attribute__((ext_vector_type(8))) short bf16x8;
typedef __attribute__((ext_vector_type(4))) short bf16x4;
typedef __attribute__((ext_vector_type(4))) float f32x4;
typedef __attribute__((ext_vector_type(8))) unsigned short u16x8;

__device__ __forceinline__ unsigned short f2bf(float f) {   // RNE fp32->bf16
    unsigned int u = __float_as_uint(f);
    return (unsigned short)((u + 0x7FFFu + ((u >> 16) & 1u)) >> 16);
}

// K=16 bf16 MFMA; guard so the host pass never touches the builtin.
__device__ __forceinline__ f32x4 mfma16(bf16x4 a, bf16x4 b, f32x4 c) {
#if defined(__HIP_DEVICE_COMPILE__)
    return __builtin_amdgcn_mfma_f32_16x16x16bf16_1k(a, b, c, 0, 0, 0);
#else
    return c;
#endif
}

// raw v_exp_f32 (2^x). R2 lesson: plain exp2f() is the PRECISE ocml path
// (denorm guards, ~5 instr) and cost +30% VALU cycles; the builtin is 1 instr.
__device__ __forceinline__ float fast_exp2(float x) {
#if defined(__HIP_DEVICE_COMPILE__)
    return __builtin_amdgcn_exp2f(x);
#else
    return exp2f(x);
#endif
}

// ---------------------------------------------------------------------------
// Launch 1: pure streaming conversions (independent blocks).
//   [0,512)    : k  fp32 -> kb  bf16   (interleaved, coalesced per instr)
//   [512,1024) : x  fp32 -> xb  bf16
//   [1024,1152): Wq fp32 -> wqb bf16
//   [1152,2176): v[b,h,t,dh] -> vt[b,h,dh,t] bf16 (64x64 LDS transpose)
// R1 post-mortem: ~15 us either way; not the lever.
// ---------------------------------------------------------------------------
__global__ __launch_bounds__(256) void conv_kernel(
    const float* __restrict__ k, const float* __restrict__ v,
    const float* __restrict__ x, const float* __restrict__ Wq,
    unsigned short* __restrict__ kb, unsigned short* __restrict__ vt,
    unsigned short* __restrict__ xb, unsigned short* __restrict__ wqb)
{
    __shared__ float Ts[64][65];
    const int tid = threadIdx.x;
    const int bi = blockIdx.x;

    if (bi < 1152) {                      // ---- flat conversions ----
        const float* src;
        unsigned short* dst;
        if (bi < 512)       { src = k  + (size_t)bi * 8192;
                              dst = kb  + (size_t)bi * 8192; }
        else if (bi < 1024) { src = x  + (size_t)(bi - 512) * 8192;
                              dst = xb  + (size_t)(bi - 512) * 8192; }
        else                { src = Wq + (size_t)(bi - 1024) * 8192;
                              dst = wqb + (size_t)(bi - 1024) * 8192; }
        #pragma unroll
        for (int u = 0; u < 8; ++u) {
            const int o = u * 1024 + tid * 4;
            const float4 a = *(const float4*)(src + o);
            ushort4 s;
            s.x = f2bf(a.x); s.y = f2bf(a.y);
            s.z = f2bf(a.z); s.w = f2bf(a.w);
            *(ushort4*)(dst + o) = s;
        }
        return;
    }

    // ---- v transpose+convert ----
    const int idx = bi - 1152;
    const int t0 = (idx & 31) * 64;
    const int hb = idx >> 5;
    const size_t bh = (size_t)(hb >> 4) * H_ + (hb & 15);
    #pragma unroll
    for (int u = 0; u < 4; ++u) {
        const int tr = u * 16 + (tid >> 4);
        const int dc = (tid & 15) * 4;
        const float4 r = *(const float4*)(v + (bh * T_ + t0 + tr) * DH_ + dc);
        Ts[tr][dc + 0] = r.x; Ts[tr][dc + 1] = r.y;
        Ts[tr][dc + 2] = r.z; Ts[tr][dc + 3] = r.w;
    }
    __syncthreads();
    #pragma unroll
    for (int u = 0; u < 4; ++u) {
        const int dh = u * 16 + (tid >> 4);
        const int tc = (tid & 15) * 4;
        ushort4 o;
        o.x = f2bf(Ts[tc + 0][dh]); o.y = f2bf(Ts[tc + 1][dh]);
        o.z = f2bf(Ts[tc + 2][dh]); o.w = f2bf(Ts[tc + 3][dh]);
        *(ushort4*)(vt + (bh * DH_ + dh) * T_ + t0 + tc) = o;
    }
}

// ---------------------------------------------------------------------------
// Launch 2: mega-attention (qproj fused). 1024 blocks, 64 q-rows each,
// 4 waves x 16 rows, 4 blocks/CU resident (16 waves/CU).
//
// R3: CHUNKED-DISPATCH-BALANCED MAP. Evidence from R0/R1/R2 counters
// supports chunked-within-XCD assignment: XCD = bi&7, and the 4 blocks
// co-resident on one CU are bi = {32c+x, 32c+8+x, 32c+16+x, 32c+24+x}
// — i.e. SAME G = bi>>5, differing in u = (bi>>3)&3 = (hb>>3).
// (Under that model R0's and R2's maps were equally imbalanced —
// per-CU work 4*(qt+1), makespan ~2x ideal — matching MfmaUtil ~20%
// and Occupancy ~34%/27%; R1's pair-map was balanced but at half
// occupancy -> 74 us.)
// Map qt = f(G,u): u0 -> G, u1 -> 31-G, u2 -> (G+1)&31, u3 -> 31-((G+1)&31).
// Each u-slice is a bijection in G (full (qt,hb) coverage) and the co-CU
// quadruple sums to 62 -> per-CU work = 66 units for EVERY CU.
// hb untouched -> per-XCD K/V L2 working set unchanged (4 heads, 2 MB).
//
// Phase 1: Q^T = Wq_h * x^T, bf16 staged, double-buffered, 1 barrier/iter.
//   acc C-layout = Q^T [dh = w*16+l4*4+r][qrow = nt*16+l15]; bounced
//   through Qs (overlaid on dead Xs1) -> B-operand Q fragments.
//   Q is scaled by (1/sqrt(D))*log2(e) so softmax runs in exp2 domain via
//   raw v_exp_f32 (fast_exp2) — R2's libm exp2f cost +30% VALU cycles.
// Phase 2: transposed-S flash loop, double-buffered K/V, stride 72,
//   1 barrier/iter, P^T in registers, O^T = V^T * P^T, fused residual.
//
// LDS regions (36864 B): phase1 Ws0=0, Xs0=9216, Ws1=18432, Xs1=27648;
// Qs=27648; phase2 Ks0=0, Ks1=9216, Vs0=18432, Vs1=27648. All reuses are
// barrier-separated.
// ---------------------------------------------------------------------------
__global__ __launch_bounds__(256, 4) void mega_attn(
    const unsigned short* __restrict__ xb,   // [B,T,D]   bf16
    const unsigned short* __restrict__ wqb,  // [D,D]     bf16
    const unsigned short* __restrict__ kb,   // [B,H,T,DH] bf16
    const unsigned short* __restrict__ vt,   // [B,H,DH,T] bf16
    const float* __restrict__ xg,            // [B,T,D] fp32 (residual)
    float* __restrict__ out)                 // [B,T,D] fp32
{
    __shared__ __align__(16) char lds_raw[36864];
    unsigned short (*Ws0)[72] = (unsigned short(*)[72])(lds_raw);
    unsigned short (*Xs0)[72] = (unsigned short(*)[72])(lds_raw + 9216);
    unsigned short (*Ws1)[72] = (unsigned short(*)[72])(lds_raw + 18432);
    unsigned short (*Xs1)[72] = (unsigned short(*)[72])(lds_raw + 27648);
    unsigned short (*Qs)[72]  = (unsigned short(*)[72])(lds_raw + 27648);
    unsigned short (*Ks0)[72] = (unsigned short(*)[72])(lds_raw);
    unsigned short (*Ks1)[72] = (unsigned short(*)[72])(lds_raw + 9216);
    unsigned short (*Vs0)[72] = (unsigned short(*)[72])(lds_raw + 18432);
    unsigned short (*Vs1)[72] = (unsigned short(*)[72])(lds_raw + 27648);

    const int tid = threadIdx.x;
    const int lane = tid & 63;
    const int w = tid >> 6;
    const int l15 = lane & 15, l4 = lane >> 4;
    const int bi = blockIdx.x;

    const int G = bi >> 5;
    const int hb = bi & 31;
    const int u_ = hb >> 3;                  // co-CU slot under chunked model
    const int Gp = (u_ & 2) ? ((G + 1) & 31) : G;
    const int qt = (u_ & 1) ? (31 - Gp) : Gp;

    const int h = hb & 15, b = hb >> 4;
    const int q0 = qt * 64;
    const size_t bh = (size_t)b * H_ + h;

    const int srow = tid >> 2;               // staging row 0..63
    const int scol = (tid & 3) * 16;         // staging col (shorts)

    // ---- Phase 1: Q^T tile build (bf16 staged, dbuf, 1 barrier/iter) ----
    f32x4 acc[4] = {};
    {
        const unsigned short* xg0 = xb  + ((size_t)b * T_ + q0 + srow) * D_ + scol;
        const unsigned short* wg0 = wqb + (size_t)(h * 64 + srow) * D_ + scol;

        // stage iter 0 into buffer 0
        uint4 xr0 = *(const uint4*)(xg0);
        uint4 xr1 = *(const uint4*)(xg0 + 8);
        uint4 wr0 = *(const uint4*)(wg0);
        uint4 wr1 = *(const uint4*)(wg0 + 8);
        *(uint4*)&Xs0[srow][scol] = xr0;
        *(uint4*)&Xs0[srow][scol + 8] = xr1;
        *(uint4*)&Ws0[srow][scol] = wr0;
        *(uint4*)&Ws0[srow][scol + 8] = wr1;
        __syncthreads();

        int p = 0;
        for (int it = 0; it < 16; ++it) {
            if (it < 15) {
                const int kk = (it + 1) * 64;
                xr0 = *(const uint4*)(xg0 + kk);
                xr1 = *(const uint4*)(xg0 + kk + 8);
                wr0 = *(const uint4*)(wg0 + kk);
                wr1 = *(const uint4*)(wg0 + kk + 8);
            }
            unsigned short (*Wp)[72] = p ? Ws1 : Ws0;
            unsigned short (*Xp)[72] = p ? Xs1 : Xs0;
            #pragma unroll
            for (int kc = 0; kc < 2; ++kc) {
                const bf16x8 wf = *(const bf16x8*)&Wp[w * 16 + l15][kc * 32 + l4 * 8];
                #pragma unroll
                for (int nt = 0; nt < 4; ++nt) {
                    const bf16x8 xf = *(const bf16x8*)&Xp[nt * 16 + l15][kc * 32 + l4 * 8];
                    acc[nt] = __builtin_amdgcn_mfma_f32_16x16x32_bf16(wf, xf, acc[nt], 0, 0, 0);
                }
            }
            if (it < 15) {
                unsigned short (*Wn)[72] = p ? Ws0 : Ws1;
                unsigned short (*Xn)[72] = p ? Xs0 : Xs1;
                *(uint4*)&Xn[srow][scol] = xr0;
                *(uint4*)&Xn[srow][scol + 8] = xr1;
                *(uint4*)&Wn[srow][scol] = wr0;
                *(uint4*)&Wn[srow][scol + 8] = wr1;
                __syncthreads();
                p ^= 1;
            }
        }
    }
    __syncthreads();   // final phase-1 buffer (Ws1/Xs1) fully consumed

    // Qs write: acc[nt][r] = Q^T[dh = w*16+l4*4+r][qrow = nt*16+l15]
    // scale folds in log2(e): softmax computed as 2^(s' - m') with
    // s' = s*log2e — weights identical to exp-domain softmax.
    {
        const float qscale = (1.0f / 32.0f) * 1.4426950408889634f;
        #pragma unroll
        for (int nt = 0; nt < 4; ++nt) {
            ushort4 o;
            o.x = f2bf(acc[nt][0] * qscale); o.y = f2bf(acc[nt][1] * qscale);
            o.z = f2bf(acc[nt][2] * qscale); o.w = f2bf(acc[nt][3] * qscale);
            *(ushort4*)&Qs[nt * 16 + l15][w * 16 + l4 * 4] = o;
        }
    }
    __syncthreads();   // all Qs writes visible (cross-wave)

    // Q B-fragments: lane l15 = qrow (w*16+l15), k = dh
    bf16x8 qf[2];
    #pragma unroll
    for (int kc = 0; kc < 2; ++kc)
        qf[kc] = *(const bf16x8*)&Qs[w * 16 + l15][kc * 32 + l4 * 8];

    f32x4 o_acc[4] = {};                     // O^T: dh = mt*16+l4*4+r, qrow = l15
    float m_i = -INFINITY, l_i = 0.0f;

    // stage tile j0=0 into buffer 0 (Ks0/Vs0 don't overlap Qs)
    {
        const unsigned short* gk = kb + (bh * T_ + srow) * DH_ + scol;
        *(uint4*)&Ks0[srow][scol] = *(const uint4*)gk;
        *(uint4*)&Ks0[srow][scol + 8] = *(const uint4*)(gk + 8);
        const unsigned short* gv = vt + (bh * DH_ + srow) * T_ + scol;
        *(uint4*)&Vs0[srow][scol] = *(const uint4*)gv;
        *(uint4*)&Vs0[srow][scol + 8] = *(const uint4*)(gv + 8);
    }
    __syncthreads();   // also orders qf reads before any later Vs1 write

    int p = 0;
    for (int j0 = 0; j0 <= q0; j0 += 64) {
        unsigned short (*Ksp)[72] = p ? Ks1 : Ks0;
        unsigned short (*Vsp)[72] = p ? Vs1 : Vs0;
        unsigned short (*Ksn)[72] = p ? Ks0 : Ks1;
        unsigned short (*Vsn)[72] = p ? Vs0 : Vs1;

        // prefetch next tile into registers (valid-but-discarded addr on last)
        const int jn = (j0 + 64 <= q0) ? j0 + 64 : 0;
        uint4 kr0, kr1, vr0, vr1;
        {
            const unsigned short* gk = kb + (bh * T_ + jn + srow) * DH_ + scol;
            kr0 = *(const uint4*)gk;
            kr1 = *(const uint4*)(gk + 8);
            const unsigned short* gv = vt + (bh * DH_ + srow) * T_ + jn + scol;
            vr0 = *(const uint4*)gv;
            vr1 = *(const uint4*)(gv + 8);
        }

        // S^T = K * Q^T : st[nt] keys nt*16 + l4*4+r, qrow = w*16+l15
        f32x4 st[4] = {};
        #pragma unroll
        for (int kc = 0; kc < 2; ++kc) {
            #pragma unroll
            for (int nt = 0; nt < 4; ++nt) {
                const bf16x8 kf = *(const bf16x8*)&Ksp[nt * 16 + l15][kc * 32 + l4 * 8];
                st[nt] = __builtin_amdgcn_mfma_f32_16x16x32_bf16(kf, qf[kc], st[nt], 0, 0, 0);
            }
        }

        // causal mask (diagonal tile only)
        if (j0 == q0) {
            const int thr = w * 16 + l15 - l4 * 4;   // mask if nt*16+r > thr
            #pragma unroll
            for (int nt = 0; nt < 4; ++nt)
                #pragma unroll
                for (int r = 0; r < 4; ++r)
                    if (nt * 16 + r > thr) st[nt][r] = -INFINITY;
        }

        // online softmax (exp2 domain): 16 in-lane values + 2-shfl butterfly
        float rm = -INFINITY;
        #pragma unroll
        for (int nt = 0; nt < 4; ++nt)
            #pragma unroll
            for (int r = 0; r < 4; ++r) rm = fmaxf(rm, st[nt][r]);
        rm = fmaxf(rm, __shfl_xor(rm, 16));
        rm = fmaxf(rm, __shfl_xor(rm, 32));
        const float mn = fmaxf(m_i, rm);
        const float alpha = fast_exp2(m_i - mn);
        float rs = 0.0f;
        #pragma unroll
        for (int nt = 0; nt < 4; ++nt)
            #pragma unroll
            for (int r = 0; r < 4; ++r) {
                const float pv = fast_exp2(st[nt][r] - mn);
                st[nt][r] = pv;
                rs += pv;
            }
        rs += __shfl_xor(rs, 16);
        rs += __shfl_xor(rs, 32);
        l_i = l_i * alpha + rs;
        m_i = mn;
        #pragma unroll
        for (int mt = 0; mt < 4; ++mt)
            #pragma unroll
            for (int r = 0; r < 4; ++r) o_acc[mt][r] *= alpha;

        // pack P^T into K=16 B-frags (v_perm truncation, 2 vals/op)
        bf16x4 pf[4];
        #pragma unroll
        for (int nt = 0; nt < 4; ++nt) {
            union { unsigned int u[2]; bf16x4 s; } cv;
            cv.u[0] = __builtin_amdgcn_perm(__float_as_uint(st[nt][1]),
                                            __float_as_uint(st[nt][0]), 0x07060302u);
            cv.u[1] = __builtin_amdgcn_perm(__float_as_uint(st[nt][3]),
                                            __float_as_uint(st[nt][2]), 0x07060302u);
            pf[nt] = cv.s;
        }

        // O^T += V^T * P^T  (A = V^T from LDS, B = P^T in registers)
        #pragma unroll
        for (int c = 0; c < 4; ++c) {
            #pragma unroll
            for (int mt = 0; mt < 4; ++mt) {
                const bf16x4 vf = *(const bf16x4*)&Vsp[mt * 16 + l15][c * 16 + l4 * 4];
                o_acc[mt] = mfma16(vf, pf[c], o_acc[mt]);
            }
        }

        // write prefetched tile to the other buffer, single barrier
        *(uint4*)&Ksn[srow][scol] = kr0;
        *(uint4*)&Ksn[srow][scol + 8] = kr1;
        *(uint4*)&Vsn[srow][scol] = vr0;
        *(uint4*)&Vsn[srow][scol + 8] = vr1;
        __syncthreads();
        p ^= 1;
    }

    // epilogue: out = x + O^T / l   (dh = mt*16 + l4*4+r, qrow = l15)
    const float inv = 1.0f / l_i;
    const int qrow = q0 + w * 16 + l15;
    #pragma unroll
    for (int mt = 0; mt < 4; ++mt) {
        #pragma unroll
        for (int r = 0; r < 4; ++r) {
            const int d = h * DH_ + mt * 16 + l4 * 4 + r;
            const size_t off = ((size_t)b * T_ + qrow) * D_ + d;
            out[off] = xg[off] + o_acc[mt][r] * inv;
        }
    }
}

extern "C" void kernel_launch(void* const* d_in, const int* in_sizes, int n_in,
                              void* d_out, int out_size, void* d_ws, size_t ws_size,
                              hipStream_t stream) {
    const float* x  = (const float*)d_in[0];
    const float* k  = (const float*)d_in[1];
    const float* v  = (const float*)d_in[2];
    const float* Wq = (const float*)d_in[3];
    float* out = (float*)d_out;

    const size_t NE = (size_t)B_ * H_ * T_ * DH_;   // 4M elements
    unsigned short* kb  = (unsigned short*)d_ws;    // 8 MB
    unsigned short* vt  = kb + NE;                  // 8 MB
    unsigned short* xb  = vt + NE;                  // 8 MB
    unsigned short* wqb = xb + NE;                  // 2 MB

    conv_kernel<<<2176, 256, 0, stream>>>(k, v, x, Wq, kb, vt, xb, wqb);
    mega_attn<<<1024, 256, 0, stream>>>(xb, wqb, kb, vt, x, out);
}

// Round 4
// 154.509 us; speedup vs baseline: 1.0531x; 1.0404x over previous
//
#include <hip/hip_runtime.h>
#include <hip/hip_bf16.h>

#define B_ 2
#define T_ 2048
#define D_ 1024
#define H_ 16
#define DH_ 64

typedef __attribute__((ext_vector_type(8))) short bf16x8;
typedef __attribute__((ext_vector_type(4))) short bf16x4;
typedef __attribute__((ext_vector_type(4))) float f32x4;
typedef __attribute__((ext_vector_type(8))) unsigned short u16x8;

__device__ __forceinline__ unsigned short f2bf(float f) {   // RNE fp32->bf16
    unsigned int u = __float_as_uint(f);
    return (unsigned short)((u + 0x7FFFu + ((u >> 16) & 1u)) >> 16);
}

// K=16 bf16 MFMA; guard so the host pass never touches the builtin.
__device__ __forceinline__ f32x4 mfma16(bf16x4 a, bf16x4 b, f32x4 c) {
#if defined(__HIP_DEVICE_COMPILE__)
    return __builtin_amdgcn_mfma_f32_16x16x16bf16_1k(a, b, c, 0, 0, 0);
#else
    return c;
#endif
}

// raw v_exp_f32 (2^x). R2 lesson: plain exp2f() is the PRECISE ocml path
// (denorm guards, ~5 instr, +30% VALU cycles); the builtin is 1 instr.
__device__ __forceinline__ float fast_exp2(float x) {
#if defined(__HIP_DEVICE_COMPILE__)
    return __builtin_amdgcn_exp2f(x);
#else
    return exp2f(x);
#endif
}

// ---------------------------------------------------------------------------
// Launch 1: pure streaming conversions (independent blocks).
//   [0,512)    : k  fp32 -> kb  bf16   (interleaved, coalesced per instr)
//   [512,1024) : x  fp32 -> xb  bf16
//   [1024,1152): Wq fp32 -> wqb bf16
//   [1152,2176): v[b,h,t,dh] -> vt[b,h,dh,t] bf16 (64x64 LDS transpose)
// R1 post-mortem: ~15 us either way; not the lever.
// ---------------------------------------------------------------------------
__global__ __launch_bounds__(256) void conv_kernel(
    const float* __restrict__ k, const float* __restrict__ v,
    const float* __restrict__ x, const float* __restrict__ Wq,
    unsigned short* __restrict__ kb, unsigned short* __restrict__ vt,
    unsigned short* __restrict__ xb, unsigned short* __restrict__ wqb)
{
    __shared__ float Ts[64][65];
    const int tid = threadIdx.x;
    const int bi = blockIdx.x;

    if (bi < 1152) {                      // ---- flat conversions ----
        const float* src;
        unsigned short* dst;
        if (bi < 512)       { src = k  + (size_t)bi * 8192;
                              dst = kb  + (size_t)bi * 8192; }
        else if (bi < 1024) { src = x  + (size_t)(bi - 512) * 8192;
                              dst = xb  + (size_t)(bi - 512) * 8192; }
        else                { src = Wq + (size_t)(bi - 1024) * 8192;
                              dst = wqb + (size_t)(bi - 1024) * 8192; }
        #pragma unroll
        for (int u = 0; u < 8; ++u) {
            const int o = u * 1024 + tid * 4;
            const float4 a = *(const float4*)(src + o);
            ushort4 s;
            s.x = f2bf(a.x); s.y = f2bf(a.y);
            s.z = f2bf(a.z); s.w = f2bf(a.w);
            *(ushort4*)(dst + o) = s;
        }
        return;
    }

    // ---- v transpose+convert ----
    const int idx = bi - 1152;
    const int t0 = (idx & 31) * 64;
    const int hb = idx >> 5;
    const size_t bh = (size_t)(hb >> 4) * H_ + (hb & 15);
    #pragma unroll
    for (int u = 0; u < 4; ++u) {
        const int tr = u * 16 + (tid >> 4);
        const int dc = (tid & 15) * 4;
        const float4 r = *(const float4*)(v + (bh * T_ + t0 + tr) * DH_ + dc);
        Ts[tr][dc + 0] = r.x; Ts[tr][dc + 1] = r.y;
        Ts[tr][dc + 2] = r.z; Ts[tr][dc + 3] = r.w;
    }
    __syncthreads();
    #pragma unroll
    for (int u = 0; u < 4; ++u) {
        const int dh = u * 16 + (tid >> 4);
        const int tc = (tid & 15) * 4;
        ushort4 o;
        o.x = f2bf(Ts[tc + 0][dh]); o.y = f2bf(Ts[tc + 1][dh]);
        o.z = f2bf(Ts[tc + 2][dh]); o.w = f2bf(Ts[tc + 3][dh]);
        *(ushort4*)(vt + (bh * DH_ + dh) * T_ + t0 + tc) = o;
    }
}

// ---------------------------------------------------------------------------
// Launch 2: mega-attention (qproj fused). 1024 blocks, 64 q-rows each,
// 4 waves x 16 rows, 4 blocks/CU resident (16 waves/CU).
//
// R4: map REVERTED to R0's proven heavy-first qt = 31 - (bi>>5).
// (R2's round-robin-balanced and R3's chunked-balanced maps BOTH lost to
// this map with lower occupancy — the bi->CU model behind each was wrong;
// stop guessing the unobservable.)  Kept from R2/R3: exp2-domain softmax
// (log2e folded into Q scale) + raw v_exp_f32 (verified: VALUBusy 29.8 ->
// 24.3). New: exact defer-max skip (alpha==1 iters skip the 16-mul
// rescale — THR=0 so it is bit-exact), s_setprio(1) around phase-2 MFMA
// clusters (4 independent blocks/CU -> role diversity; T5 attn evidence),
// and the dead last-iteration LDS write+barrier removed.
//
// Phase 1: Q^T = Wq_h * x^T, bf16 staged, double-buffered, 1 barrier/iter.
//   acc C-layout = Q^T [dh = w*16+l4*4+r][qrow = nt*16+l15]; bounced
//   through Qs (overlaid on dead Xs1) -> B-operand Q fragments.
// Phase 2: transposed-S flash loop, double-buffered K/V, stride 72,
//   1 barrier/iter, P^T in registers, O^T = V^T * P^T, fused residual.
//
// LDS regions (36864 B): phase1 Ws0=0, Xs0=9216, Ws1=18432, Xs1=27648;
// Qs=27648; phase2 Ks0=0, Ks1=9216, Vs0=18432, Vs1=27648. All reuses are
// barrier-separated.
// ---------------------------------------------------------------------------
__global__ __launch_bounds__(256, 4) void mega_attn(
    const unsigned short* __restrict__ xb,   // [B,T,D]   bf16
    const unsigned short* __restrict__ wqb,  // [D,D]     bf16
    const unsigned short* __restrict__ kb,   // [B,H,T,DH] bf16
    const unsigned short* __restrict__ vt,   // [B,H,DH,T] bf16
    const float* __restrict__ xg,            // [B,T,D] fp32 (residual)
    float* __restrict__ out)                 // [B,T,D] fp32
{
    __shared__ __align__(16) char lds_raw[36864];
    unsigned short (*Ws0)[72] = (unsigned short(*)[72])(lds_raw);
    unsigned short (*Xs0)[72] = (unsigned short(*)[72])(lds_raw + 9216);
    unsigned short (*Ws1)[72] = (unsigned short(*)[72])(lds_raw + 18432);
    unsigned short (*Xs1)[72] = (unsigned short(*)[72])(lds_raw + 27648);
    unsigned short (*Qs)[72]  = (unsigned short(*)[72])(lds_raw + 27648);
    unsigned short (*Ks0)[72] = (unsigned short(*)[72])(lds_raw);
    unsigned short (*Ks1)[72] = (unsigned short(*)[72])(lds_raw + 9216);
    unsigned short (*Vs0)[72] = (unsigned short(*)[72])(lds_raw + 18432);
    unsigned short (*Vs1)[72] = (unsigned short(*)[72])(lds_raw + 27648);

    const int tid = threadIdx.x;
    const int lane = tid & 63;
    const int w = tid >> 6;
    const int l15 = lane & 15, l4 = lane >> 4;
    const int bi = blockIdx.x;

    const int qt = 31 - (bi >> 5);           // R0's proven heavy-first map
    const int hb = bi & 31;
    const int h = hb & 15, b = hb >> 4;
    const int q0 = qt * 64;
    const size_t bh = (size_t)b * H_ + h;

    const int srow = tid >> 2;               // staging row 0..63
    const int scol = (tid & 3) * 16;         // staging col (shorts)

    // ---- Phase 1: Q^T tile build (bf16 staged, dbuf, 1 barrier/iter) ----
    f32x4 acc[4] = {};
    {
        const unsigned short* xg0 = xb  + ((size_t)b * T_ + q0 + srow) * D_ + scol;
        const unsigned short* wg0 = wqb + (size_t)(h * 64 + srow) * D_ + scol;

        // stage iter 0 into buffer 0
        uint4 xr0 = *(const uint4*)(xg0);
        uint4 xr1 = *(const uint4*)(xg0 + 8);
        uint4 wr0 = *(const uint4*)(wg0);
        uint4 wr1 = *(const uint4*)(wg0 + 8);
        *(uint4*)&Xs0[srow][scol] = xr0;
        *(uint4*)&Xs0[srow][scol + 8] = xr1;
        *(uint4*)&Ws0[srow][scol] = wr0;
        *(uint4*)&Ws0[srow][scol + 8] = wr1;
        __syncthreads();

        int p = 0;
        for (int it = 0; it < 16; ++it) {
            if (it < 15) {
                const int kk = (it + 1) * 64;
                xr0 = *(const uint4*)(xg0 + kk);
                xr1 = *(const uint4*)(xg0 + kk + 8);
                wr0 = *(const uint4*)(wg0 + kk);
                wr1 = *(const uint4*)(wg0 + kk + 8);
            }
            unsigned short (*Wp)[72] = p ? Ws1 : Ws0;
            unsigned short (*Xp)[72] = p ? Xs1 : Xs0;
            #pragma unroll
            for (int kc = 0; kc < 2; ++kc) {
                const bf16x8 wf = *(const bf16x8*)&Wp[w * 16 + l15][kc * 32 + l4 * 8];
                #pragma unroll
                for (int nt = 0; nt < 4; ++nt) {
                    const bf16x8 xf = *(const bf16x8*)&Xp[nt * 16 + l15][kc * 32 + l4 * 8];
                    acc[nt] = __builtin_amdgcn_mfma_f32_16x16x32_bf16(wf, xf, acc[nt], 0, 0, 0);
                }
            }
            if (it < 15) {
                unsigned short (*Wn)[72] = p ? Ws0 : Ws1;
                unsigned short (*Xn)[72] = p ? Xs0 : Xs1;
                *(uint4*)&Xn[srow][scol] = xr0;
                *(uint4*)&Xn[srow][scol + 8] = xr1;
                *(uint4*)&Wn[srow][scol] = wr0;
                *(uint4*)&Wn[srow][scol + 8] = wr1;
                __syncthreads();
                p ^= 1;
            }
        }
    }
    __syncthreads();   // final phase-1 buffer (Ws1/Xs1) fully consumed

    // Qs write: acc[nt][r] = Q^T[dh = w*16+l4*4+r][qrow = nt*16+l15]
    // scale folds in log2(e): softmax computed as 2^(s' - m') with
    // s' = s*log2e — weights identical to exp-domain softmax.
    {
        const float qscale = (1.0f / 32.0f) * 1.4426950408889634f;
        #pragma unroll
        for (int nt = 0; nt < 4; ++nt) {
            ushort4 o;
            o.x = f2bf(acc[nt][0] * qscale); o.y = f2bf(acc[nt][1] * qscale);
            o.z = f2bf(acc[nt][2] * qscale); o.w = f2bf(acc[nt][3] * qscale);
            *(ushort4*)&Qs[nt * 16 + l15][w * 16 + l4 * 4] = o;
        }
    }
    __syncthreads();   // all Qs writes visible (cross-wave)

    // Q B-fragments: lane l15 = qrow (w*16+l15), k = dh
    bf16x8 qf[2];
    #pragma unroll
    for (int kc = 0; kc < 2; ++kc)
        qf[kc] = *(const bf16x8*)&Qs[w * 16 + l15][kc * 32 + l4 * 8];

    f32x4 o_acc[4] = {};                     // O^T: dh = mt*16+l4*4+r, qrow = l15
    float m_i = -INFINITY, l_i = 0.0f;

    // stage tile j0=0 into buffer 0 (Ks0/Vs0 don't overlap Qs)
    {
        const unsigned short* gk = kb + (bh * T_ + srow) * DH_ + scol;
        *(uint4*)&Ks0[srow][scol] = *(const uint4*)gk;
        *(uint4*)&Ks0[srow][scol + 8] = *(const uint4*)(gk + 8);
        const unsigned short* gv = vt + (bh * DH_ + srow) * T_ + scol;
        *(uint4*)&Vs0[srow][scol] = *(const uint4*)gv;
        *(uint4*)&Vs0[srow][scol + 8] = *(const uint4*)(gv + 8);
    }
    __syncthreads();   // also orders qf reads before any later Vs1 write

    int p = 0;
    for (int j0 = 0; j0 <= q0; j0 += 64) {
        unsigned short (*Ksp)[72] = p ? Ks1 : Ks0;
        unsigned short (*Vsp)[72] = p ? Vs1 : Vs0;
        unsigned short (*Ksn)[72] = p ? Ks0 : Ks1;
        unsigned short (*Vsn)[72] = p ? Vs0 : Vs1;
        const bool more = (j0 < q0);

        // prefetch next tile into registers
        const int jn = more ? j0 + 64 : 0;
        uint4 kr0, kr1, vr0, vr1;
        {
            const unsigned short* gk = kb + (bh * T_ + jn + srow) * DH_ + scol;
            kr0 = *(const uint4*)gk;
            kr1 = *(const uint4*)(gk + 8);
            const unsigned short* gv = vt + (bh * DH_ + srow) * T_ + jn + scol;
            vr0 = *(const uint4*)gv;
            vr1 = *(const uint4*)(gv + 8);
        }

        // S^T = K * Q^T : st[nt] keys nt*16 + l4*4+r, qrow = w*16+l15
        f32x4 st[4] = {};
        __builtin_amdgcn_s_setprio(1);
        #pragma unroll
        for (int kc = 0; kc < 2; ++kc) {
            #pragma unroll
            for (int nt = 0; nt < 4; ++nt) {
                const bf16x8 kf = *(const bf16x8*)&Ksp[nt * 16 + l15][kc * 32 + l4 * 8];
                st[nt] = __builtin_amdgcn_mfma_f32_16x16x32_bf16(kf, qf[kc], st[nt], 0, 0, 0);
            }
        }
        __builtin_amdgcn_s_setprio(0);

        // causal mask (diagonal tile only)
        if (j0 == q0) {
            const int thr = w * 16 + l15 - l4 * 4;   // mask if nt*16+r > thr
            #pragma unroll
            for (int nt = 0; nt < 4; ++nt)
                #pragma unroll
                for (int r = 0; r < 4; ++r)
                    if (nt * 16 + r > thr) st[nt][r] = -INFINITY;
        }

        // online softmax (exp2 domain): 16 in-lane values + 2-shfl butterfly
        float rm = -INFINITY;
        #pragma unroll
        for (int nt = 0; nt < 4; ++nt)
            #pragma unroll
            for (int r = 0; r < 4; ++r) rm = fmaxf(rm, st[nt][r]);
        rm = fmaxf(rm, __shfl_xor(rm, 16));
        rm = fmaxf(rm, __shfl_xor(rm, 32));

        if (__all(rm <= m_i)) {
            // EXACT defer-max skip: mn == m_i, alpha == 2^0 == 1 — no
            // rescale of o_acc/l_i needed, identical arithmetic result.
            float rs = 0.0f;
            #pragma unroll
            for (int nt = 0; nt < 4; ++nt)
                #pragma unroll
                for (int r = 0; r < 4; ++r) {
                    const float pv = fast_exp2(st[nt][r] - m_i);
                    st[nt][r] = pv;
                    rs += pv;
                }
            rs += __shfl_xor(rs, 16);
            rs += __shfl_xor(rs, 32);
            l_i += rs;
        } else {
            const float mn = fmaxf(m_i, rm);
            const float alpha = fast_exp2(m_i - mn);
            float rs = 0.0f;
            #pragma unroll
            for (int nt = 0; nt < 4; ++nt)
                #pragma unroll
                for (int r = 0; r < 4; ++r) {
                    const float pv = fast_exp2(st[nt][r] - mn);
                    st[nt][r] = pv;
                    rs += pv;
                }
            rs += __shfl_xor(rs, 16);
            rs += __shfl_xor(rs, 32);
            l_i = l_i * alpha + rs;
            m_i = mn;
            #pragma unroll
            for (int mt = 0; mt < 4; ++mt)
                #pragma unroll
                for (int r = 0; r < 4; ++r) o_acc[mt][r] *= alpha;
        }

        // pack P^T into K=16 B-frags (v_perm truncation, 2 vals/op)
        bf16x4 pf[4];
        #pragma unroll
        for (int nt = 0; nt < 4; ++nt) {
            union { unsigned int u[2]; bf16x4 s; } cv;
            cv.u[0] = __builtin_amdgcn_perm(__float_as_uint(st[nt][1]),
                                            __float_as_uint(st[nt][0]), 0x07060302u);
            cv.u[1] = __builtin_amdgcn_perm(__float_as_uint(st[nt][3]),
                                            __float_as_uint(st[nt][2]), 0x07060302u);
            pf[nt] = cv.s;
        }

        // O^T += V^T * P^T  (A = V^T from LDS, B = P^T in registers)
        __builtin_amdgcn_s_setprio(1);
        #pragma unroll
        for (int c = 0; c < 4; ++c) {
            #pragma unroll
            for (int mt = 0; mt < 4; ++mt) {
                const bf16x4 vf = *(const bf16x4*)&Vsp[mt * 16 + l15][c * 16 + l4 * 4];
                o_acc[mt] = mfma16(vf, pf[c], o_acc[mt]);
            }
        }
        __builtin_amdgcn_s_setprio(0);

        // write prefetched tile to the other buffer, single barrier.
        // Skipped entirely on the final iteration (condition is
        // block-uniform; epilogue touches no LDS).
        if (more) {
            *(uint4*)&Ksn[srow][scol] = kr0;
            *(uint4*)&Ksn[srow][scol + 8] = kr1;
            *(uint4*)&Vsn[srow][scol] = vr0;
            *(uint4*)&Vsn[srow][scol + 8] = vr1;
            __syncthreads();
            p ^= 1;
        }
    }

    // epilogue: out = x + O^T / l   (dh = mt*16 + l4*4+r, qrow = l15)
    const float inv = 1.0f / l_i;
    const int qrow = q0 + w * 16 + l15;
    #pragma unroll
    for (int mt = 0; mt < 4; ++mt) {
        #pragma unroll
        for (int r = 0; r < 4; ++r) {
            const int d = h * DH_ + mt * 16 + l4 * 4 + r;
            const size_t off = ((size_t)b * T_ + qrow) * D_ + d;
            out[off] = xg[off] + o_acc[mt][r] * inv;
        }
    }
}

extern "C" void kernel_launch(void* const* d_in, const int* in_sizes, int n_in,
                              void* d_out, int out_size, void* d_ws, size_t ws_size,
                              hipStream_t stream) {
    const float* x  = (const float*)d_in[0];
    const float* k  = (const float*)d_in[1];
    const float* v  = (const float*)d_in[2];
    const float* Wq = (const float*)d_in[3];
    float* out = (float*)d_out;

    const size_t NE = (size_t)B_ * H_ * T_ * DH_;   // 4M elements
    unsigned short* kb  = (unsigned short*)d_ws;    // 8 MB
    unsigned short* vt  = kb + NE;                  // 8 MB
    unsigned short* xb  = vt + NE;                  // 8 MB
    unsigned short* wqb = xb + NE;                  // 2 MB

    conv_kernel<<<2176, 256, 0, stream>>>(k, v, x, Wq, kb, vt, xb, wqb);
    mega_attn<<<1024, 256, 0, stream>>>(xb, wqb, kb, vt, x, out);
}